// Round 5
// baseline (623.361 us; speedup 1.0000x reference)
//
#include <hip/hip_runtime.h>
#include <math.h>

#define BB 8
#define NN 10000
#define EE 320000
#define IND 16
#define EH 32
#define EOUT 22
#define NOUT 16

__device__ __forceinline__ float sigmf(float x) {
    return __fdividef(1.0f, 1.0f + __expf(-x));
}

// ---------------- kernel 0: init min/max slots ----------------
__global__ void init_mm(unsigned* mm) {
    int t = threadIdx.x;
    if (t < 2) mm[t] = 0x7F7FFFFFu;       // +FLT_MAX bits (min slots)
    else if (t < 4) mm[t] = 0u;           // 0 (max slots; values are >= 0)
}

// ---------------- kernel 1: edge_attr column min/max ----------------
// Non-negative floats: bit pattern preserves order -> uint atomics.
__global__ __launch_bounds__(256) void minmax_kernel(const float* __restrict__ ea,
                                                     unsigned* __restrict__ mm) {
    int t = blockIdx.x * 256 + threadIdx.x;
    float2 v = ((const float2*)ea)[t];
    float mn0 = v.x, mx0 = v.x, mn1 = v.y, mx1 = v.y;
    #pragma unroll
    for (int off = 32; off >= 1; off >>= 1) {
        mn0 = fminf(mn0, __shfl_xor(mn0, off));
        mx0 = fmaxf(mx0, __shfl_xor(mx0, off));
        mn1 = fminf(mn1, __shfl_xor(mn1, off));
        mx1 = fmaxf(mx1, __shfl_xor(mx1, off));
    }
    if ((threadIdx.x & 63) == 0) {
        atomicMin(&mm[0], __float_as_uint(mn0));
        atomicMin(&mm[1], __float_as_uint(mn1));
        atomicMax(&mm[2], __float_as_uint(mx0));
        atomicMax(&mm[3], __float_as_uint(mx1));
    }
}

// ---------------- kernel 2: per-node precompute ----------------
// pre1[b,n,:] = x[b,n,:] @ W1[0:16,:]   (src contribution)
// pre2[b,n,:] = x[b,n,:] @ W1[16:32,:]  (tgt contribution)
// wind[b,n]   = (speed, direc) de-normalized
__global__ __launch_bounds__(256) void node_pre(const float* __restrict__ x,
                                                const float* __restrict__ W1,
                                                const float* __restrict__ wmin,
                                                const float* __restrict__ wmax,
                                                float* __restrict__ pre1,
                                                float* __restrict__ pre2,
                                                float* __restrict__ wind) {
    int id = blockIdx.x * 256 + threadIdx.x;
    if (id >= BB * NN) return;
    float xv[16];
    const float4* xp = (const float4*)(x + (size_t)id * 16);
    #pragma unroll
    for (int q = 0; q < 4; q++) {
        float4 v = xp[q];
        xv[4 * q + 0] = v.x; xv[4 * q + 1] = v.y;
        xv[4 * q + 2] = v.z; xv[4 * q + 3] = v.w;
    }
    float s1[32], s2[32];
    #pragma unroll
    for (int j = 0; j < 32; j++) { s1[j] = 0.f; s2[j] = 0.f; }
    #pragma unroll
    for (int r = 0; r < 16; r++) {
        float xr = xv[r];
        #pragma unroll
        for (int j = 0; j < 32; j++) {
            s1[j] = fmaf(xr, W1[r * 32 + j], s1[j]);
            s2[j] = fmaf(xr, W1[(16 + r) * 32 + j], s2[j]);
        }
    }
    float4* o1 = (float4*)(pre1 + (size_t)id * 32);
    float4* o2 = (float4*)(pre2 + (size_t)id * 32);
    #pragma unroll
    for (int q = 0; q < 8; q++) {
        o1[q] = make_float4(s1[4*q], s1[4*q+1], s1[4*q+2], s1[4*q+3]);
        o2[q] = make_float4(s2[4*q], s2[4*q+1], s2[4*q+2], s2[4*q+3]);
    }
    float sp = xv[14] * (wmax[0] - wmin[0]) + wmin[0];
    float dr = xv[15] * (wmax[1] - wmin[1]) + wmin[1];
    ((float2*)wind)[id] = make_float2(sp, dr);
}

// ---------------- kernel 3: main edge kernel ----------------
// One thread = one (b, e). Accumulates g = e_feat @ Wn into out via atomics,
// with an LDS transpose so each wave atomic touches 4 cache lines.
__global__ __launch_bounds__(256) void edge_kernel(const int* __restrict__ ei,
                                                   const float* __restrict__ ea,
                                                   const float* __restrict__ pre1,
                                                   const float* __restrict__ pre2,
                                                   const float* __restrict__ wind,
                                                   const float* __restrict__ mm,
                                                   const float* __restrict__ W1,
                                                   const float* __restrict__ b1,
                                                   const float* __restrict__ W2,
                                                   const float* __restrict__ b2,
                                                   const float* __restrict__ Wn,
                                                   float* __restrict__ out) {
    __shared__ float gs[256 * 17];     // padded: stride 17 dwords
    __shared__ int nd[512];            // [0:256) tgt, [256:512) src

    const int tid = threadIdx.x;
    const int e = blockIdx.x * 256 + tid;
    const int b = blockIdx.y;

    const int src = ei[e];
    const int tgt = ei[EE + e];
    const float2 eav = ((const float2*)ea)[e];
    const float2 wv = ((const float2*)wind)[(size_t)b * NN + src];

    // edge weight
    float theta = fabsf(eav.y - wv.y);
    float ew = fmaxf(__fdividef(wv.x * cosf(theta), eav.x), 0.f);

    // normalized edge attrs (mm holds bit-identical floats)
    float ean0 = __fdividef(eav.x - mm[0], mm[2] - mm[0]);
    float ean1 = __fdividef(eav.y - mm[1], mm[3] - mm[1]);

    // first layer: pre_src + pre_tgt + per-edge terms, sigmoid
    float h[32];
    const float4* p1 = (const float4*)(pre1 + ((size_t)b * NN + src) * 32);
    const float4* p2 = (const float4*)(pre2 + ((size_t)b * NN + tgt) * 32);
    #pragma unroll
    for (int q = 0; q < 8; q++) {
        float4 a = p1[q];
        float4 c = p2[q];
        h[4*q+0] = a.x + c.x; h[4*q+1] = a.y + c.y;
        h[4*q+2] = a.z + c.z; h[4*q+3] = a.w + c.w;
    }
    #pragma unroll
    for (int j = 0; j < 32; j++) {
        float v = h[j] + ean0 * W1[32 * 32 + j] + ean1 * W1[33 * 32 + j]
                        + ew * W1[34 * 32 + j] + b1[j];
        h[j] = sigmf(v);
    }

    // second layer: h @ W2 + b2, sigmoid
    float ef[22];
    #pragma unroll
    for (int k = 0; k < 22; k++) ef[k] = b2[k];
    #pragma unroll
    for (int j = 0; j < 32; j++) {
        float hv = h[j];
        #pragma unroll
        for (int k = 0; k < 22; k++) ef[k] = fmaf(hv, W2[j * 22 + k], ef[k]);
    }
    #pragma unroll
    for (int k = 0; k < 22; k++) ef[k] = sigmf(ef[k]);

    // fold the output projection: g = e_feat @ Wn (16 floats = one cache line)
    float g[16];
    #pragma unroll
    for (int i = 0; i < 16; i++) g[i] = 0.f;
    #pragma unroll
    for (int k = 0; k < 22; k++) {
        float ev = ef[k];
        #pragma unroll
        for (int i = 0; i < 16; i++) g[i] = fmaf(ev, Wn[k * 16 + i], g[i]);
    }

    // transpose through LDS, then line-coalesced atomics
    nd[tid] = tgt;
    nd[256 + tid] = src;
    #pragma unroll
    for (int i = 0; i < 16; i++) gs[tid * 17 + i] = g[i];
    __syncthreads();

    const int c = tid & 15;        // component
    const int base = tid >> 4;     // edge sub-slot 0..15
    float* aggb = out + (size_t)b * NN * 16;
    for (int p = 0; p < 16; p++) {
        int s = base + p * 16;
        float val = gs[s * 17 + c];
        int t2 = nd[s];
        int s2 = nd[256 + s];
        atomicAdd(&aggb[(size_t)t2 * 16 + c], val);
        atomicAdd(&aggb[(size_t)s2 * 16 + c], -val);
    }
}

// ---------------- kernel 4: epilogue sigmoid(+bn) in place ----------------
__global__ __launch_bounds__(256) void epilogue(float* __restrict__ out,
                                                const float* __restrict__ bn) {
    int id = blockIdx.x * 256 + threadIdx.x;   // quad index
    if (id >= BB * NN * 4) return;
    float4 v = ((float4*)out)[id];
    int q = (id & 3) * 4;
    v.x = sigmf(v.x + bn[q + 0]);
    v.y = sigmf(v.y + bn[q + 1]);
    v.z = sigmf(v.z + bn[q + 2]);
    v.w = sigmf(v.w + bn[q + 3]);
    ((float4*)out)[id] = v;
}

extern "C" void kernel_launch(void* const* d_in, const int* in_sizes, int n_in,
                              void* d_out, int out_size, void* d_ws, size_t ws_size,
                              hipStream_t stream) {
    const float* x    = (const float*)d_in[0];
    const int*   ei   = (const int*)d_in[1];
    const float* ea   = (const float*)d_in[2];
    const float* wmin = (const float*)d_in[3];
    const float* wmax = (const float*)d_in[4];
    const float* W1   = (const float*)d_in[5];
    const float* b1   = (const float*)d_in[6];
    const float* W2   = (const float*)d_in[7];
    const float* b2   = (const float*)d_in[8];
    const float* Wn   = (const float*)d_in[9];
    const float* bn   = (const float*)d_in[10];
    float* out = (float*)d_out;

    float* ws   = (float*)d_ws;
    unsigned* mm = (unsigned*)ws;          // 16 floats (4 used)
    float* wind = ws + 16;                 // B*N*2
    float* pre1 = wind + 2 * BB * NN;      // B*N*32
    float* pre2 = pre1 + 32 * (size_t)BB * NN;

    hipMemsetAsync(d_out, 0, (size_t)out_size * sizeof(float), stream);
    init_mm<<<1, 64, 0, stream>>>(mm);
    minmax_kernel<<<EE / 256, 256, 0, stream>>>(ea, mm);
    node_pre<<<(BB * NN + 255) / 256, 256, 0, stream>>>(x, W1, wmin, wmax, pre1, pre2, wind);
    edge_kernel<<<dim3(EE / 256, BB), 256, 0, stream>>>(ei, ea, pre1, pre2, wind,
                                                        (const float*)mm, W1, b1, W2, b2, Wn, out);
    epilogue<<<(BB * NN * 4 + 255) / 256, 256, 0, stream>>>(out, bn);
}